// Round 4
// baseline (184.479 us; speedup 1.0000x reference)
//
#include <hip/hip_runtime.h>

#define IC 64
#define OC 64
#define NSH 45
#define BATCH 2048
#define PI_F 3.14159265358979323846f
#define WF_FLOATS (NSH * IC * OC)   // 184,320 floats = 737,280 B

// 4B-aligned vector types (x rows are only 4B-aligned: stride 45 floats)
typedef float f4 __attribute__((ext_vector_type(4), aligned(4)));
typedef float f2 __attribute__((ext_vector_type(2), aligned(8)));

// ---------------- weight fold: wf[c][i][o] = w[o][i][ls[c]/2] * sqrt(pi/(2l+1))
__global__ __launch_bounds__(256) void fold_kernel(const float* __restrict__ w,
                                                   const int* __restrict__ ls,
                                                   float* __restrict__ wf) {
    int t = blockIdx.x * 256 + threadIdx.x;   // [0, 45*64*16)
    if (t >= NSH * IC * 16) return;
    int o4 = t & 15;
    int i  = (t >> 4) & 63;
    int c  = t >> 10;                          // [0, 45)
    int l  = ls[c];
    int l2 = l >> 1;
    float sc = sqrtf(PI_F / (2.0f * (float)l + 1.0f));
    int o0 = o4 * 4;
    f4 v;
    v[0] = w[((o0 + 0) * IC + i) * 5 + l2] * sc;
    v[1] = w[((o0 + 1) * IC + i) * 5 + l2] * sc;
    v[2] = w[((o0 + 2) * IC + i) * 5 + l2] * sc;
    v[3] = w[((o0 + 3) * IC + i) * 5 + l2] * sc;
    *(f4*)(wf + ((size_t)c * IC + i) * OC + o0) = v;
}

// Load one i-slice into named stage buffers (all-static indexing -> registers)
#define LOAD1(X, W, i)                                                  \
    X[0] = *(const f4*)(xpi + (size_t)(i) * NSH);                       \
    X[1] = *(const f4*)(xpi2 + (size_t)(i) * NSH);                      \
    W[0] = *(const f2*)(wpi + (size_t)(i) * OC);                        \
    W[1] = *(const f2*)(wpi + (size_t)(IC * OC) + (size_t)(i) * OC);    \
    W[2] = *(const f2*)(wpi + (size_t)(2 * IC * OC) + (size_t)(i) * OC);\
    W[3] = *(const f2*)(wpi + (size_t)(3 * IC * OC) + (size_t)(i) * OC);

#define COMP1(X, W)                                                     \
    {                                                                   \
        _Pragma("unroll") for (int bb = 0; bb < 2; ++bb)                \
            _Pragma("unroll") for (int oo = 0; oo < 2; ++oo)            \
                _Pragma("unroll") for (int cc = 0; cc < 4; ++cc)        \
                    acc[bb][oo][cc] =                                   \
                        fmaf(X[bb][cc], W[cc][oo], acc[bb][oo][cc]);    \
    }

// ---------------- main kernel: software-pipelined, no LDS.
// Grid 1536 = 64 bt (32 b) x 4 ot (16 o) x 6 ct (8 c).  Block 256 thr.
// Thread = (bq 16) x (og 8) x (cq 2); tile 2b x 2o x 4c = 16 outputs.
__global__ __launch_bounds__(256, 4) void sph_folded(const float* __restrict__ x,
                                                     const float* __restrict__ w,
                                                     float* __restrict__ out) {
    // bijective XCD swizzle (1536 % 8 == 0): each XCD owns 8 consecutive bt
    int wg  = (int)(blockIdx.x & 7) * 192 + (int)(blockIdx.x >> 3);
    int bt  = wg / 24;
    int rem = wg - bt * 24;
    int ot  = rem / 6;
    int ct  = rem - ot * 6;

    int tid = threadIdx.x;
    int cq  = tid & 1;
    int og  = (tid >> 1) & 7;
    int bq  = tid >> 4;                        // [0, 16)

    int cqg = ct * 2 + cq;                     // [0, 12)
    int c0  = cqg < 11 ? cqg * 4 : 41;         // overlapping last quad covers 0..44
    int o0  = ot * 16 + og * 2;
    int b0  = bt * 32 + bq * 2;

    const float* xpi  = x + (size_t)b0 * (IC * NSH) + c0;
    const float* xpi2 = xpi + (size_t)(IC * NSH);          // row b0+1
    const float* wpi  = w + (size_t)c0 * (IC * OC) + o0;   // wf[c0][i][o0]

    float acc[2][2][4];
#pragma unroll
    for (int bb = 0; bb < 2; ++bb)
#pragma unroll
        for (int oo = 0; oo < 2; ++oo)
#pragma unroll
            for (int cc = 0; cc < 4; ++cc) acc[bb][oo][cc] = 0.0f;

    f4 AX[2]; f2 AW[4];
    f4 BX[2]; f2 BW[4];

    // 2-stage software pipeline over i: >=6 loads always in flight.
    LOAD1(AX, AW, 0);
    LOAD1(BX, BW, 1);
#pragma unroll 1
    for (int ii = 0; ii < 62; ii += 2) {
        COMP1(AX, AW);
        LOAD1(AX, AW, ii + 2);
        COMP1(BX, BW);
        LOAD1(BX, BW, ii + 3);
    }
    COMP1(AX, AW);   // i = 62
    COMP1(BX, BW);   // i = 63

    float* op = out + ((size_t)b0 * OC + o0) * NSH + c0;
#pragma unroll
    for (int bb = 0; bb < 2; ++bb)
#pragma unroll
        for (int oo = 0; oo < 2; ++oo) {
            f4 r;
            r[0] = acc[bb][oo][0]; r[1] = acc[bb][oo][1];
            r[2] = acc[bb][oo][2]; r[3] = acc[bb][oo][3];
            *(f4*)(op + ((size_t)bb * OC + oo) * NSH) = r;
        }
}

// ---------------- fallback (tiny ws): correct but unoptimized
__global__ __launch_bounds__(128) void sph_raw(const float* __restrict__ x,
                                               const float* __restrict__ w,
                                               const int* __restrict__ ls,
                                               float* __restrict__ out) {
    int t = blockIdx.x * 128 + threadIdx.x;    // one thread per (b, o)
    if (t >= BATCH * OC) return;
    int o = t & 63;
    int b = t >> 6;
    float res[NSH];
#pragma unroll 1
    for (int c = 0; c < NSH; ++c) res[c] = 0.0f;
#pragma unroll 1
    for (int i = 0; i < IC; ++i) {
        const float* xr = x + ((size_t)b * IC + i) * NSH;
        const float* wr = w + ((size_t)o * IC + i) * 5;
        float wl[5];
#pragma unroll
        for (int l2 = 0; l2 < 5; ++l2) wl[l2] = wr[l2];
#pragma unroll 1
        for (int c = 0; c < NSH; ++c) res[c] = fmaf(xr[c], wl[ls[c] >> 1], res[c]);
    }
#pragma unroll 1
    for (int c = 0; c < NSH; ++c) {
        float sc = sqrtf(PI_F / (2.0f * (float)ls[c] + 1.0f));
        out[((size_t)b * OC + o) * NSH + c] = res[c] * sc;
    }
}

extern "C" void kernel_launch(void* const* d_in, const int* in_sizes, int n_in,
                              void* d_out, int out_size, void* d_ws, size_t ws_size,
                              hipStream_t stream) {
    const float* x  = (const float*)d_in[0];
    const float* wt = (const float*)d_in[1];
    const int*   ls = (const int*)d_in[2];
    float* out = (float*)d_out;

    if (ws_size >= (size_t)WF_FLOATS * sizeof(float)) {
        float* wf = (float*)d_ws;
        fold_kernel<<<(NSH * IC * 16 + 255) / 256, 256, 0, stream>>>(wt, ls, wf);
        sph_folded<<<64 * 4 * 6, 256, 0, stream>>>(x, wf, out);
    } else {
        sph_raw<<<(BATCH * OC + 127) / 128, 128, 0, stream>>>(x, wt, ls, out);
    }
}

// Round 5
// 168.972 us; speedup vs baseline: 1.0918x; 1.0918x over previous
//
#include <hip/hip_runtime.h>

#define IC 64
#define OC 64
#define NSH 45
#define BATCH 2048
#define PI_F 3.14159265358979323846f
#define WF_FLOATS (NSH * IC * OC)   // 184,320 floats = 737,280 B

typedef float f4 __attribute__((ext_vector_type(4), aligned(4)));

// ---------------- weight fold: wf[c][i][o] = w[o][i][ls[c]/2] * sqrt(pi/(2l+1))
__global__ __launch_bounds__(256) void fold_kernel(const float* __restrict__ w,
                                                   const int* __restrict__ ls,
                                                   float* __restrict__ wf) {
    int t = blockIdx.x * 256 + threadIdx.x;   // [0, 45*64*16)
    if (t >= NSH * IC * 16) return;
    int o4 = t & 15;
    int i  = (t >> 4) & 63;
    int c  = t >> 10;                          // [0, 45)
    int l  = ls[c];
    int l2 = l >> 1;
    float sc = sqrtf(PI_F / (2.0f * (float)l + 1.0f));
    int o0 = o4 * 4;
    f4 v;
    v[0] = w[((o0 + 0) * IC + i) * 5 + l2] * sc;
    v[1] = w[((o0 + 1) * IC + i) * 5 + l2] * sc;
    v[2] = w[((o0 + 2) * IC + i) * 5 + l2] * sc;
    v[3] = w[((o0 + 3) * IC + i) * 5 + l2] * sc;
    *(f4*)(wf + ((size_t)c * IC + i) * OC + o0) = v;
}

// ---------------- main kernel: lanes = 64 batch rows; w wave-uniform (s_load);
// x staged via LDS (reg-staged, double-buffered); thread tile 16o x 4c.
// Grid 768 = 32 b-chunks(64 rows) x 12 c-groups(4 c) x 2 o-quad-pairs.
// Block 128 thr = 2 waves = 2 o-quads of 16.
__global__ __launch_bounds__(128) void sph_scalar_w(const float* __restrict__ x,
                                                    const float* __restrict__ wf,
                                                    float* __restrict__ out) {
    __shared__ float xs[2][8][64][4];          // 16 KB double-buffered chunk

    // bijective XCD swizzle (768 % 8 == 0): bid%8=k -> b-chunks [4k,4k+4):
    // all 24 blocks of a b-chunk share one XCD's L2 (x 2.95 MB + w 737 KB fit).
    int bid  = blockIdx.x;
    int wgid = (bid & 7) * 96 + (bid >> 3);
    int bch  = wgid / 24;
    int sub  = wgid - bch * 24;
    int cg   = sub >> 1;                       // [0,12)
    int oqp  = sub & 1;

    int tid  = threadIdx.x;
    int lane = tid & 63;
    int wv   = tid >> 6;                       // wave id 0..1
    int c0   = cg < 11 ? cg * 4 : 41;          // overlapping last quad covers 0..44
    int o0   = (oqp * 2 + wv) * 16;
    o0 = __builtin_amdgcn_readfirstlane(o0);   // pin wave-uniform -> scalar w path
    int b0   = bch * 64;

    // per-lane global x base: row (b0+lane), coeff slice c0 (f4, 4B-aligned ok)
    const float* xrowbase = x + ((size_t)(b0 + lane) * IC) * NSH + c0;

    float acc[16][4];
#pragma unroll
    for (int oo = 0; oo < 16; ++oo)
#pragma unroll
        for (int cc = 0; cc < 4; ++cc) acc[oo][cc] = 0.0f;

    f4 stg[4];

    // chunk staging: segment (s,bb): s = q*2+wv, bb = lane  (contiguous ds_write_b128)
#define LOADCHUNK(k)                                                          \
    {                                                                         \
        _Pragma("unroll") for (int q = 0; q < 4; ++q) {                       \
            int s = q * 2 + wv;                                               \
            stg[q] = *(const f4*)(xrowbase + (size_t)((k) * 8 + s) * NSH);    \
        }                                                                     \
    }
#define WRITECHUNK(buf)                                                       \
    {                                                                         \
        _Pragma("unroll") for (int q = 0; q < 4; ++q) {                       \
            int s = q * 2 + wv;                                               \
            *(f4*)(&xs[buf][s][lane][0]) = stg[q];                            \
        }                                                                     \
    }

    LOADCHUNK(0);
    WRITECHUNK(0);
    __syncthreads();

#pragma unroll 1
    for (int k = 0; k < 8; ++k) {
        if (k < 7) LOADCHUNK(k + 1);           // issue next chunk's loads early (T14)
#pragma unroll
        for (int s = 0; s < 8; ++s) {
            int i = k * 8 + s;
            f4 xv = *(const f4*)(&xs[k & 1][s][lane][0]);   // ds_read_b128, contiguous
            float wvv[4][16];                  // wave-uniform -> s_load_dwordx16 x4
#pragma unroll
            for (int cc = 0; cc < 4; ++cc) {
                const float* wp = wf + ((size_t)(c0 + cc) * IC + i) * OC + o0;
#pragma unroll
                for (int oo = 0; oo < 16; ++oo) wvv[cc][oo] = wp[oo];
            }
#pragma unroll
            for (int oo = 0; oo < 16; ++oo)
#pragma unroll
                for (int cc = 0; cc < 4; ++cc)
                    acc[oo][cc] = fmaf(xv[cc], wvv[cc][oo], acc[oo][cc]);
        }
        if (k < 7) {
            WRITECHUNK((k + 1) & 1);           // compiler waits stg here, not earlier
            __syncthreads();
        }
    }

    // store: 16 x dwordx4; c41-43 written twice by cg10/11 with identical values
    float* op = out + ((size_t)(b0 + lane) * OC + o0) * NSH + c0;
#pragma unroll
    for (int oo = 0; oo < 16; ++oo) {
        f4 r;
        r[0] = acc[oo][0]; r[1] = acc[oo][1]; r[2] = acc[oo][2]; r[3] = acc[oo][3];
        *(f4*)(op + (size_t)oo * NSH) = r;
    }
}

// ---------------- fallback (tiny ws): correct but unoptimized
__global__ __launch_bounds__(128) void sph_raw(const float* __restrict__ x,
                                               const float* __restrict__ w,
                                               const int* __restrict__ ls,
                                               float* __restrict__ out) {
    int t = blockIdx.x * 128 + threadIdx.x;    // one thread per (b, o)
    if (t >= BATCH * OC) return;
    int o = t & 63;
    int b = t >> 6;
    float res[NSH];
#pragma unroll 1
    for (int c = 0; c < NSH; ++c) res[c] = 0.0f;
#pragma unroll 1
    for (int i = 0; i < IC; ++i) {
        const float* xr = x + ((size_t)b * IC + i) * NSH;
        const float* wr = w + ((size_t)o * IC + i) * 5;
        float wl[5];
#pragma unroll
        for (int l2 = 0; l2 < 5; ++l2) wl[l2] = wr[l2];
#pragma unroll 1
        for (int c = 0; c < NSH; ++c) res[c] = fmaf(xr[c], wl[ls[c] >> 1], res[c]);
    }
#pragma unroll 1
    for (int c = 0; c < NSH; ++c) {
        float sc = sqrtf(PI_F / (2.0f * (float)ls[c] + 1.0f));
        out[((size_t)b * OC + o) * NSH + c] = res[c] * sc;
    }
}

extern "C" void kernel_launch(void* const* d_in, const int* in_sizes, int n_in,
                              void* d_out, int out_size, void* d_ws, size_t ws_size,
                              hipStream_t stream) {
    const float* x  = (const float*)d_in[0];
    const float* wt = (const float*)d_in[1];
    const int*   ls = (const int*)d_in[2];
    float* out = (float*)d_out;

    if (ws_size >= (size_t)WF_FLOATS * sizeof(float)) {
        float* wf = (float*)d_ws;
        fold_kernel<<<(NSH * IC * 16 + 255) / 256, 256, 0, stream>>>(wt, ls, wf);
        sph_scalar_w<<<768, 128, 0, stream>>>(x, wf, out);
    } else {
        sph_raw<<<(BATCH * OC + 127) / 128, 128, 0, stream>>>(x, wt, ls, out);
    }
}

// Round 6
// 118.432 us; speedup vs baseline: 1.5577x; 1.4267x over previous
//
#include <hip/hip_runtime.h>

#define IC 64
#define OC 64
#define NSH 45
#define BATCH 2048
#define PI_F 3.14159265358979323846f
#define WF_FLOATS (NSH * IC * OC)   // 184,320 floats = 737,280 B

typedef float f4 __attribute__((ext_vector_type(4), aligned(4)));

// ---------------- weight fold: wf[c][i][o] = w[o][i][ls[c]/2] * sqrt(pi/(2l+1))
__global__ __launch_bounds__(256) void fold_kernel(const float* __restrict__ w,
                                                   const int* __restrict__ ls,
                                                   float* __restrict__ wf) {
    int t = blockIdx.x * 256 + threadIdx.x;   // [0, 45*64*16)
    if (t >= NSH * IC * 16) return;
    int o4 = t & 15;
    int i  = (t >> 4) & 63;
    int c  = t >> 10;                          // [0, 45)
    int l  = ls[c];
    int l2 = l >> 1;
    float sc = sqrtf(PI_F / (2.0f * (float)l + 1.0f));
    int o0 = o4 * 4;
    f4 v;
    v[0] = w[((o0 + 0) * IC + i) * 5 + l2] * sc;
    v[1] = w[((o0 + 1) * IC + i) * 5 + l2] * sc;
    v[2] = w[((o0 + 2) * IC + i) * 5 + l2] * sc;
    v[3] = w[((o0 + 3) * IC + i) * 5 + l2] * sc;
    *(f4*)(wf + ((size_t)c * IC + i) * OC + o0) = v;
}

// ---------------- main kernel
// Hot loop touches ONLY LDS (single lgkm source -> compiler emits counted
// lgkmcnt and pipelines ds_reads). w staged to LDS once; x double-buffered
// in 8-i chunks with T14 split (loads issued before compute, writes after).
// Block 256 thr = 4 waves; lanes = 64 batch rows; tile 64b x 32o x 4c;
// per wave 8o x 4c = 32 acc. LDS 48 KB -> 3 blocks/CU, grid 768 = 3.0/CU.
__global__ __launch_bounds__(256) void sph_lds(const float* __restrict__ x,
                                               const float* __restrict__ wf,
                                               float* __restrict__ out) {
    __shared__ float wl[4 * 64 * 32];      // 32 KB: [c][i][o32]
    __shared__ float xs[2][8 * 64 * 4];    // 16 KB: [buf][i8][b64][c4]

    // XCD swizzle (768 = 8*96): all 24 (cg,oh) blocks of a b-chunk share one
    // XCD's L2 -> out-lines (split across 4 cg-blocks) merge before writeback.
    int bid  = blockIdx.x;
    int wgid = (bid & 7) * 96 + (bid >> 3);
    int bch  = wgid / 24;                  // [0,32)
    int sub  = wgid - bch * 24;
    int cg   = sub >> 1;                   // [0,12)
    int oh   = sub & 1;

    int tid  = threadIdx.x;
    int lane = tid & 63;
    int wv   = tid >> 6;                   // wave id [0,4)
    int c0   = cg < 11 ? cg * 4 : 41;      // overlapping last quad covers 0..44
    int o0   = oh * 32;
    int b0   = bch * 64;

    // ---- stage w slice: wl[c][i][o32] (coalesced global reads, once) ----
#pragma unroll
    for (int j = 0; j < 8; ++j) {
        int s   = tid + 256 * j;           // [0,2048) f4-slots
        int c   = s >> 9;
        int rem = s & 511;
        int i   = rem >> 3;
        int oq  = rem & 7;
        f4 v = *(const f4*)(wf + ((size_t)(c0 + c) * IC + i) * OC + o0 + oq * 4);
        *(f4*)(&wl[(c * 64 + i) * 32 + oq * 4]) = v;
    }

    // ---- x staging: 2 f4-slots per thread per chunk ----
    int s0  = tid, s1 = tid + 256;         // slot = i*64 + b
    int si0 = s0 >> 6, sb0 = s0 & 63;
    int si1 = s1 >> 6, sb1 = s1 & 63;
    const float* xb0 = x + ((size_t)(b0 + sb0) * IC) * NSH + c0;
    const float* xb1 = x + ((size_t)(b0 + sb1) * IC) * NSH + c0;

    f4 st0 = *(const f4*)(xb0 + (size_t)si0 * NSH);
    f4 st1 = *(const f4*)(xb1 + (size_t)si1 * NSH);
    *(f4*)(&xs[0][(si0 * 64 + sb0) * 4]) = st0;
    *(f4*)(&xs[0][(si1 * 64 + sb1) * 4]) = st1;
    __syncthreads();

    float acc[8][4];
#pragma unroll
    for (int oo = 0; oo < 8; ++oo)
#pragma unroll
        for (int cc = 0; cc < 4; ++cc) acc[oo][cc] = 0.0f;

    const int ow = wv * 8;                 // wave's o-offset within the 32

#pragma unroll 1
    for (int k = 0; k < 8; ++k) {
        if (k < 7) {                       // T14: issue next chunk's loads early
            st0 = *(const f4*)(xb0 + (size_t)((k + 1) * 8 + si0) * NSH);
            st1 = *(const f4*)(xb1 + (size_t)((k + 1) * 8 + si1) * NSH);
        }
        const float* xbuf = &xs[k & 1][0];
#pragma unroll
        for (int s = 0; s < 8; ++s) {
            int i = k * 8 + s;
            f4 xv = *(const f4*)(xbuf + (s * 64 + lane) * 4);   // 2-way max
            f4 wq[4][2];                   // broadcast uniform-address reads
#pragma unroll
            for (int cc = 0; cc < 4; ++cc) {
                wq[cc][0] = *(const f4*)(&wl[(cc * 64 + i) * 32 + ow]);
                wq[cc][1] = *(const f4*)(&wl[(cc * 64 + i) * 32 + ow + 4]);
            }
#pragma unroll
            for (int oo = 0; oo < 8; ++oo)
#pragma unroll
                for (int cc = 0; cc < 4; ++cc)
                    acc[oo][cc] = fmaf(xv[cc], wq[cc][oo >> 2][oo & 3], acc[oo][cc]);
        }
        if (k < 7) {                       // vmcnt wait lands here, hidden by FMAs
            *(f4*)(&xs[(k + 1) & 1][(si0 * 64 + sb0) * 4]) = st0;
            *(f4*)(&xs[(k + 1) & 1][(si1 * 64 + sb1) * 4]) = st1;
            __syncthreads();
        }
    }

    // ---- store: 8 x dwordx4 per thread; c41-43 dup-written with equal values
    float* op = out + ((size_t)(b0 + lane) * OC + o0 + ow) * NSH + c0;
#pragma unroll
    for (int oo = 0; oo < 8; ++oo) {
        f4 r;
        r[0] = acc[oo][0]; r[1] = acc[oo][1]; r[2] = acc[oo][2]; r[3] = acc[oo][3];
        *(f4*)(op + (size_t)oo * NSH) = r;
    }
}

// ---------------- fallback (tiny ws): correct but unoptimized
__global__ __launch_bounds__(128) void sph_raw(const float* __restrict__ x,
                                               const float* __restrict__ w,
                                               const int* __restrict__ ls,
                                               float* __restrict__ out) {
    int t = blockIdx.x * 128 + threadIdx.x;    // one thread per (b, o)
    if (t >= BATCH * OC) return;
    int o = t & 63;
    int b = t >> 6;
    float res[NSH];
#pragma unroll 1
    for (int c = 0; c < NSH; ++c) res[c] = 0.0f;
#pragma unroll 1
    for (int i = 0; i < IC; ++i) {
        const float* xr = x + ((size_t)b * IC + i) * NSH;
        const float* wr = w + ((size_t)o * IC + i) * 5;
        float wl5[5];
#pragma unroll
        for (int l2 = 0; l2 < 5; ++l2) wl5[l2] = wr[l2];
#pragma unroll 1
        for (int c = 0; c < NSH; ++c) res[c] = fmaf(xr[c], wl5[ls[c] >> 1], res[c]);
    }
#pragma unroll 1
    for (int c = 0; c < NSH; ++c) {
        float sc = sqrtf(PI_F / (2.0f * (float)ls[c] + 1.0f));
        out[((size_t)b * OC + o) * NSH + c] = res[c] * sc;
    }
}

extern "C" void kernel_launch(void* const* d_in, const int* in_sizes, int n_in,
                              void* d_out, int out_size, void* d_ws, size_t ws_size,
                              hipStream_t stream) {
    const float* x  = (const float*)d_in[0];
    const float* wt = (const float*)d_in[1];
    const int*   ls = (const int*)d_in[2];
    float* out = (float*)d_out;

    if (ws_size >= (size_t)WF_FLOATS * sizeof(float)) {
        float* wf = (float*)d_ws;
        fold_kernel<<<(NSH * IC * 16 + 255) / 256, 256, 0, stream>>>(wt, ls, wf);
        sph_lds<<<768, 256, 0, stream>>>(x, wf, out);
    } else {
        sph_raw<<<(BATCH * OC + 127) / 128, 128, 0, stream>>>(x, wt, ls, out);
    }
}